// Round 1
// baseline (61.827 us; speedup 1.0000x reference)
//
#include <hip/hip_runtime.h>

// Chamfer loss: X, Y f32 [8, 3, 4096] -> scalar mean of (d1+d2)/2.
// dir 0: queries = X points, targets = Y (gives d2 = min over Y per X point)
// dir 1: queries = Y points, targets = X (gives d1 = min over X per Y point)

constexpr int NPTS  = 4096;
constexpr int NB    = 8;
constexpr int TPB   = 256;
constexpr int TILES = NPTS / TPB;        // 16
constexpr int BLOCKS = 2 * NB * TILES;   // 256

__global__ __launch_bounds__(TPB, 1) void chamfer_partial(
    const float* __restrict__ X, const float* __restrict__ Y,
    float* __restrict__ partial)
{
    __shared__ float4 s[NPTS];           // 64 KB: (tx, ty, tz, ||t||^2)
    __shared__ float wsum[TPB / 64];

    const int bid  = blockIdx.x;
    const int dir  = bid >> 7;           // 0..1
    const int rem  = bid & 127;
    const int b    = rem >> 4;           // 0..7
    const int tile = rem & 15;           // 0..15

    const float* __restrict__ Qb = (dir ? Y : X) + b * 3 * NPTS;
    const float* __restrict__ Tb = (dir ? X : Y) + b * 3 * NPTS;

    // Stage target cloud into LDS, coalesced per coordinate plane.
    for (int i = threadIdx.x; i < NPTS; i += TPB) {
        float tx = Tb[i];
        float ty = Tb[NPTS + i];
        float tz = Tb[2 * NPTS + i];
        s[i] = make_float4(tx, ty, tz, fmaf(tx, tx, fmaf(ty, ty, tz * tz)));
    }
    __syncthreads();

    const int q = tile * TPB + threadIdx.x;
    const float qx = Qb[q];
    const float qy = Qb[NPTS + q];
    const float qz = Qb[2 * NPTS + q];
    const float ra = fmaf(qx, qx, fmaf(qy, qy, qz * qz));
    const float nx = -2.0f * qx, ny = -2.0f * qy, nz = -2.0f * qz;

    // ||q-t||^2 = ra + rt - 2 q.t  (5 VALU per target: add, 3 fma, min)
    float m0 = 3.4e38f, m1 = 3.4e38f, m2 = 3.4e38f, m3 = 3.4e38f;
    #pragma unroll 4
    for (int m = 0; m < NPTS; m += 4) {
        float4 p0 = s[m + 0];
        float4 p1 = s[m + 1];
        float4 p2 = s[m + 2];
        float4 p3 = s[m + 3];
        float t0 = fmaf(nz, p0.z, fmaf(ny, p0.y, fmaf(nx, p0.x, ra + p0.w)));
        float t1 = fmaf(nz, p1.z, fmaf(ny, p1.y, fmaf(nx, p1.x, ra + p1.w)));
        float t2 = fmaf(nz, p2.z, fmaf(ny, p2.y, fmaf(nx, p2.x, ra + p2.w)));
        float t3 = fmaf(nz, p3.z, fmaf(ny, p3.y, fmaf(nx, p3.x, ra + p3.w)));
        m0 = fminf(m0, t0);
        m1 = fminf(m1, t1);
        m2 = fminf(m2, t2);
        m3 = fminf(m3, t3);
    }
    float v = fminf(fminf(m0, m1), fminf(m2, m3));

    // Block sum of per-query mins (fixed-order, deterministic).
    #pragma unroll
    for (int off = 32; off > 0; off >>= 1) v += __shfl_down(v, off);
    if ((threadIdx.x & 63) == 0) wsum[threadIdx.x >> 6] = v;
    __syncthreads();
    if (threadIdx.x == 0) {
        float acc = 0.0f;
        #pragma unroll
        for (int i = 0; i < TPB / 64; ++i) acc += wsum[i];
        partial[bid] = acc;
    }
}

__global__ __launch_bounds__(TPB) void chamfer_reduce(
    const float* __restrict__ partial, float* __restrict__ out)
{
    __shared__ float wsum[TPB / 64];
    float v = partial[threadIdx.x];     // exactly BLOCKS == TPB partials
    #pragma unroll
    for (int off = 32; off > 0; off >>= 1) v += __shfl_down(v, off);
    if ((threadIdx.x & 63) == 0) wsum[threadIdx.x >> 6] = v;
    __syncthreads();
    if (threadIdx.x == 0) {
        float acc = 0.0f;
        #pragma unroll
        for (int i = 0; i < TPB / 64; ++i) acc += wsum[i];
        // mean over [B, N] of (d1+d2)/2  ->  total / (2*8*4096)
        out[0] = acc * (1.0f / (2.0f * NB * NPTS));
    }
}

extern "C" void kernel_launch(void* const* d_in, const int* in_sizes, int n_in,
                              void* d_out, int out_size, void* d_ws, size_t ws_size,
                              hipStream_t stream) {
    const float* X = (const float*)d_in[0];
    const float* Y = (const float*)d_in[1];
    float* partial = (float*)d_ws;      // BLOCKS floats
    float* out     = (float*)d_out;

    chamfer_partial<<<BLOCKS, TPB, 0, stream>>>(X, Y, partial);
    chamfer_reduce<<<1, TPB, 0, stream>>>(partial, out);
}

// Round 2
// 40.224 us; speedup vs baseline: 1.5371x; 1.5371x over previous
//
#include <hip/hip_runtime.h>

// Chamfer loss: X, Y f32 [8, 3, 4096] -> scalar mean of (d1+d2)/2.
// dir 0: queries = X, targets = Y; dir 1: queries = Y, targets = X.
//
// Main kernel: Q=8 queries/thread (register-tiled), targets split into
// TS=16 slices across blocks -> 512 blocks (2/CU, 2 waves/SIMD).
// Cross-slice per-query min via atomicMin on uint bits (distances >= 0).

constexpr int NPTS = 4096;
constexpr int NB   = 8;
constexpr int TPB  = 256;
constexpr int Q    = 8;                    // queries per thread
constexpr int QT   = NPTS / (TPB * Q);     // 2 query tiles per (dir,b)
constexpr int TS   = 16;                   // target slices
constexpr int TGT  = NPTS / TS;            // 256 targets per slice (== TPB)
constexpr int MAIN_BLOCKS = 2 * NB * QT * TS;  // 512
constexpr int NQ_TOTAL    = 2 * NB * NPTS;     // 65536 query slots
constexpr int RED_BLOCKS  = NQ_TOTAL / TPB;    // 256

__global__ __launch_bounds__(TPB, 2) void chamfer_main(
    const float* __restrict__ X, const float* __restrict__ Y,
    unsigned* __restrict__ minbits)
{
    __shared__ float4 s[TGT];   // 4 KB: (tx, ty, tz, ||t||^2)

    const int bid = blockIdx.x;
    const int ts  = bid & (TS - 1);
    int rest      = bid >> 4;
    const int qt  = rest & (QT - 1);
    rest >>= 1;
    const int b   = rest & (NB - 1);
    const int dir = rest >> 3;

    const float* __restrict__ Qb = (dir ? Y : X) + b * 3 * NPTS;
    const float* __restrict__ Tb = (dir ? X : Y) + b * 3 * NPTS;

    // Stage this block's target slice (TGT == TPB: one point per thread).
    {
        const int i = ts * TGT + threadIdx.x;
        float tx = Tb[i];
        float ty = Tb[NPTS + i];
        float tz = Tb[2 * NPTS + i];
        s[threadIdx.x] = make_float4(tx, ty, tz,
                                     fmaf(tx, tx, fmaf(ty, ty, tz * tz)));
    }
    __syncthreads();

    // Load Q=8 queries per thread (strided by TPB -> coalesced).
    float nx[Q], ny[Q], nz[Q], ra[Q], mn[Q];
    const int qbase = qt * (TPB * Q) + threadIdx.x;
    #pragma unroll
    for (int k = 0; k < Q; ++k) {
        const int q = qbase + k * TPB;
        float qx = Qb[q];
        float qy = Qb[NPTS + q];
        float qz = Qb[2 * NPTS + q];
        ra[k] = fmaf(qx, qx, fmaf(qy, qy, qz * qz));
        nx[k] = -2.0f * qx;
        ny[k] = -2.0f * qy;
        nz[k] = -2.0f * qz;
        mn[k] = 3.4e38f;
    }

    // ||q-t||^2 = ra + rt - 2 q.t  (~5 VALU/distance; 1 ds_read_b128 per
    // target amortized over Q=8 queries).
    for (int m = 0; m < TGT; m += 2) {
        float4 p0 = s[m + 0];
        float4 p1 = s[m + 1];
        #pragma unroll
        for (int k = 0; k < Q; ++k) {
            float d0 = fmaf(nz[k], p0.z,
                        fmaf(ny[k], p0.y, fmaf(nx[k], p0.x, ra[k] + p0.w)));
            float d1 = fmaf(nz[k], p1.z,
                        fmaf(ny[k], p1.y, fmaf(nx[k], p1.x, ra[k] + p1.w)));
            mn[k] = fminf(mn[k], fminf(d0, d1));
        }
    }

    // Cross-slice combine: atomicMin on uint bits (valid for floats >= 0;
    // order-independent -> deterministic). Consecutive lanes hit
    // consecutive addresses -> coalesced.
    unsigned* mb = minbits + (dir * NB + b) * NPTS + qbase;
    #pragma unroll
    for (int k = 0; k < Q; ++k) {
        float v = fmaxf(mn[k], 0.0f);
        atomicMin(&mb[k * TPB], __float_as_uint(v));
    }
}

__global__ __launch_bounds__(TPB) void chamfer_reduce1(
    const unsigned* __restrict__ minbits, float* __restrict__ partial)
{
    __shared__ float wsum[TPB / 64];
    const int idx = blockIdx.x * TPB + threadIdx.x;
    float v = __uint_as_float(minbits[idx]);
    #pragma unroll
    for (int off = 32; off > 0; off >>= 1) v += __shfl_down(v, off);
    if ((threadIdx.x & 63) == 0) wsum[threadIdx.x >> 6] = v;
    __syncthreads();
    if (threadIdx.x == 0) {
        float acc = 0.0f;
        #pragma unroll
        for (int i = 0; i < TPB / 64; ++i) acc += wsum[i];
        partial[blockIdx.x] = acc;
    }
}

__global__ __launch_bounds__(TPB) void chamfer_reduce2(
    const float* __restrict__ partial, float* __restrict__ out)
{
    __shared__ float wsum[TPB / 64];
    float v = partial[threadIdx.x];   // exactly RED_BLOCKS == TPB partials
    #pragma unroll
    for (int off = 32; off > 0; off >>= 1) v += __shfl_down(v, off);
    if ((threadIdx.x & 63) == 0) wsum[threadIdx.x >> 6] = v;
    __syncthreads();
    if (threadIdx.x == 0) {
        float acc = 0.0f;
        #pragma unroll
        for (int i = 0; i < TPB / 64; ++i) acc += wsum[i];
        // mean over [B, N] of (d1+d2)/2  ->  total / (2*8*4096)
        out[0] = acc * (1.0f / (2.0f * NB * NPTS));
    }
}

extern "C" void kernel_launch(void* const* d_in, const int* in_sizes, int n_in,
                              void* d_out, int out_size, void* d_ws, size_t ws_size,
                              hipStream_t stream) {
    const float* X = (const float*)d_in[0];
    const float* Y = (const float*)d_in[1];

    unsigned* minbits = (unsigned*)d_ws;                    // 65536 u32 (256 KB)
    float*    partial = (float*)((char*)d_ws + NQ_TOTAL * sizeof(unsigned));
    float*    out     = (float*)d_out;

    // 0x7F7F7F7F as uint > any non-negative distance's bits (~3.39e38 as f32).
    hipMemsetAsync(minbits, 0x7F, NQ_TOTAL * sizeof(unsigned), stream);
    chamfer_main<<<MAIN_BLOCKS, TPB, 0, stream>>>(X, Y, minbits);
    chamfer_reduce1<<<RED_BLOCKS, TPB, 0, stream>>>(minbits, partial);
    chamfer_reduce2<<<1, TPB, 0, stream>>>(partial, out);
}

// Round 3
// 35.052 us; speedup vs baseline: 1.7639x; 1.1475x over previous
//
#include <hip/hip_runtime.h>

// Chamfer loss: X, Y f32 [8, 3, 4096] -> scalar mean of (d1+d2)/2.
// dir 0: queries = X, targets = Y; dir 1: queries = Y, targets = X.
//
// main: Q=8 queries/thread, TS=32 target slices -> 1024 blocks (4/CU).
//   inner loop computes d' = rt - 2 q.t (3 FMA/distance, ra hoisted out);
//   per-slice min written to minslice[ts][qslot] (no atomics, no memset).
// reduce1: min over 32 slices per qslot, sum within block -> partial[128].
// reduce2: fixed-order sum of 128 partials -> scalar.

constexpr int NPTS = 4096;
constexpr int NB   = 8;
constexpr int TPB  = 256;
constexpr int Q    = 8;                    // queries per thread
constexpr int QT   = NPTS / (TPB * Q);     // 2 query tiles per (dir,b)
constexpr int TS   = 32;                   // target slices
constexpr int TGT  = NPTS / TS;            // 128 targets per slice
constexpr int MAIN_BLOCKS = 2 * NB * QT * TS;  // 1024
constexpr int NQ_TOTAL    = 2 * NB * NPTS;     // 65536 query slots
constexpr int RB1 = 128;                   // reduce1 blocks

__global__ __launch_bounds__(TPB, 4) void chamfer_main(
    const float* __restrict__ X, const float* __restrict__ Y,
    float* __restrict__ minslice)
{
    __shared__ float4 s[TGT];   // 2 KB: (tx, ty, tz, ||t||^2)

    const int bid = blockIdx.x;
    const int ts  = bid & (TS - 1);
    int rest      = bid >> 5;
    const int qt  = rest & (QT - 1);
    rest >>= 1;
    const int b   = rest & (NB - 1);
    const int dir = rest >> 3;

    const float* __restrict__ Qb = (dir ? Y : X) + b * 3 * NPTS;
    const float* __restrict__ Tb = (dir ? X : Y) + b * 3 * NPTS;

    // Stage this block's target slice (TGT=128 < TPB).
    if (threadIdx.x < TGT) {
        const int i = ts * TGT + threadIdx.x;
        float tx = Tb[i];
        float ty = Tb[NPTS + i];
        float tz = Tb[2 * NPTS + i];
        s[threadIdx.x] = make_float4(tx, ty, tz,
                                     fmaf(tx, tx, fmaf(ty, ty, tz * tz)));
    }
    __syncthreads();

    // Load Q=8 queries per thread (stride TPB -> coalesced).
    float nx[Q], ny[Q], nz[Q], ra[Q], mn[Q];
    const int qbase = qt * (TPB * Q) + threadIdx.x;
    #pragma unroll
    for (int k = 0; k < Q; ++k) {
        const int q = qbase + k * TPB;
        float qx = Qb[q];
        float qy = Qb[NPTS + q];
        float qz = Qb[2 * NPTS + q];
        ra[k] = fmaf(qx, qx, fmaf(qy, qy, qz * qz));
        nx[k] = -2.0f * qx;
        ny[k] = -2.0f * qy;
        nz[k] = -2.0f * qz;
        mn[k] = 3.4e38f;
    }

    // d' = rt - 2 q.t : 3 FMA per distance; min folded as v_min3 pairs.
    // min_t(||q-t||^2) = ra + min_t(d').
    for (int m = 0; m < TGT; m += 4) {
        float4 p0 = s[m + 0];
        float4 p1 = s[m + 1];
        float4 p2 = s[m + 2];
        float4 p3 = s[m + 3];
        #pragma unroll
        for (int k = 0; k < Q; ++k) {
            float d0 = fmaf(nx[k], p0.x, fmaf(ny[k], p0.y, fmaf(nz[k], p0.z, p0.w)));
            float d1 = fmaf(nx[k], p1.x, fmaf(ny[k], p1.y, fmaf(nz[k], p1.z, p1.w)));
            float d2 = fmaf(nx[k], p2.x, fmaf(ny[k], p2.y, fmaf(nz[k], p2.z, p2.w)));
            float d3 = fmaf(nx[k], p3.x, fmaf(ny[k], p3.y, fmaf(nz[k], p3.z, p3.w)));
            mn[k] = fminf(mn[k], fminf(d0, d1));   // -> v_min3
            mn[k] = fminf(mn[k], fminf(d2, d3));   // -> v_min3
        }
    }

    // Per-slice result: ra + slice-min. Coalesced stores, disjoint per block.
    float* out = minslice + ts * NQ_TOTAL + (dir * NB + b) * NPTS + qbase;
    #pragma unroll
    for (int k = 0; k < Q; ++k) {
        out[k * TPB] = ra[k] + mn[k];
    }
}

__global__ __launch_bounds__(TPB) void chamfer_reduce1(
    const float* __restrict__ minslice, float* __restrict__ partial)
{
    __shared__ float wsum[TPB / 64];
    // 512 qslots per block, 2 per thread.
    const int q0 = blockIdx.x * 512 + threadIdx.x;
    const int q1 = q0 + 256;
    float m0 = minslice[q0];
    float m1 = minslice[q1];
    #pragma unroll
    for (int ts = 1; ts < TS; ++ts) {
        m0 = fminf(m0, minslice[ts * NQ_TOTAL + q0]);
        m1 = fminf(m1, minslice[ts * NQ_TOTAL + q1]);
    }
    float v = m0 + m1;
    #pragma unroll
    for (int off = 32; off > 0; off >>= 1) v += __shfl_down(v, off);
    if ((threadIdx.x & 63) == 0) wsum[threadIdx.x >> 6] = v;
    __syncthreads();
    if (threadIdx.x == 0) {
        float acc = 0.0f;
        #pragma unroll
        for (int i = 0; i < TPB / 64; ++i) acc += wsum[i];
        partial[blockIdx.x] = acc;
    }
}

__global__ __launch_bounds__(128) void chamfer_reduce2(
    const float* __restrict__ partial, float* __restrict__ out)
{
    __shared__ float wsum[2];
    float v = partial[threadIdx.x];   // exactly RB1 == 128 partials
    #pragma unroll
    for (int off = 32; off > 0; off >>= 1) v += __shfl_down(v, off);
    if ((threadIdx.x & 63) == 0) wsum[threadIdx.x >> 6] = v;
    __syncthreads();
    if (threadIdx.x == 0) {
        // mean over [B, N] of (d1+d2)/2  ->  total / (2*8*4096)
        out[0] = (wsum[0] + wsum[1]) * (1.0f / (2.0f * NB * NPTS));
    }
}

extern "C" void kernel_launch(void* const* d_in, const int* in_sizes, int n_in,
                              void* d_out, int out_size, void* d_ws, size_t ws_size,
                              hipStream_t stream) {
    const float* X = (const float*)d_in[0];
    const float* Y = (const float*)d_in[1];

    float* minslice = (float*)d_ws;                       // 32*65536 f32 = 8 MB
    float* partial  = (float*)((char*)d_ws + (size_t)TS * NQ_TOTAL * sizeof(float));
    float* out      = (float*)d_out;

    chamfer_main<<<MAIN_BLOCKS, TPB, 0, stream>>>(X, Y, minslice);
    chamfer_reduce1<<<RB1, TPB, 0, stream>>>(minslice, partial);
    chamfer_reduce2<<<1, 128, 0, stream>>>(partial, out);
}